// Round 12
// baseline (78.049 us; speedup 1.0000x reference)
//
#include <hip/hip_runtime.h>
#include <math.h>

#define BB 256
#define VV 4096
#define DD 64
#define NCHUNK 32
#define CHB 16384   // chunk bytes: 64 rows x 64 d x 4 B

typedef __attribute__((ext_vector_type(8))) _Float16 f16x8;
typedef __attribute__((ext_vector_type(2))) __fp16 fp16x2;   // cvt_pkrtz return type
typedef __attribute__((ext_vector_type(4))) float f32x4;
typedef __attribute__((address_space(3))) void lds_void_t;
typedef const __attribute__((address_space(1))) void gvoid_t;

// ---------------------------------------------------------------------------
// Kernel 1: 512 blocks of 256 thr (4 waves): block = (a, v-half).
// 2 blocks/CU (66 KB LDS each) -> two INDEPENDENT barrier domains per CU:
// while one block's waves sit at their per-chunk barrier, the other block's
// waves on the same SIMDs compute (r11 lesson: the all-wave lockstep barrier,
// not pipeline depth, was the binding overhead).
// Per block: 2048 rows in 32 chunks of 64 rows; 4 LDS buffers, depth-2
// counted vmcnt(8) (r10's winning params), one raw s_barrier per chunk.
// Wave cg owns cols [64cg, 64cg+64) exclusively -> epilogue stores per-wave
// top-2 partials directly (no cross-wave merge LDS). lse merges the halves.
// ---------------------------------------------------------------------------
__global__ __launch_bounds__(256) void topk_sim_kernel(
    const float* __restrict__ F, const float* __restrict__ lan,
    float* __restrict__ max0P, float* __restrict__ max1P)
{
  extern __shared__ __align__(16) char smem[];   // 4 x 16KB chunk buffers

  const int t = threadIdx.x;
  const int a    = blockIdx.x >> 1;
  const int half = blockIdx.x & 1;
  const int wave = t >> 6;       // = cg in [0,4)
  const int lane = t & 63;
  const int cl = lane & 15;      // row (A) / col (B/C) within 16x16 tile
  const int o  = lane >> 4;      // k-octet group
  const int cg = wave;           // col quarter

  const char* gFa = (const char*)(F + (size_t)a * VV * DD
                                  + (size_t)half * 2048 * DD);

  // pre-swizzled per-lane global source offsets (G21: linear LDS dest,
  // inverse-swizzled source, swizzled read).  Wave stages rows [16w,16w+16).
  int soff[4];
#pragma unroll
  for (int i = 0; i < 4; ++i) {
    int row = wave * 16 + i * 4 + o;             // row in [0,64)
    soff[i] = row * 256 + (cl ^ (row & 7)) * 16;
  }

  auto stage = [&](int ch, char* buf) {
    const char* g = gFa + (size_t)ch * CHB;
    char* dst = buf + wave * 4096;               // wave-uniform base
#pragma unroll
    for (int i = 0; i < 4; ++i) {
      __builtin_amdgcn_global_load_lds(
          (gvoid_t*)(g + soff[i]),
          (lds_void_t*)(dst + i * 1024), 16, 0, 0);
    }
  };

  // ---- B fragment GLOBAL LOADS FIRST (older than all staging DMAs) ----
  float4 bu[4][2][2];
#pragma unroll
  for (int ct = 0; ct < 4; ++ct)
#pragma unroll
    for (int s = 0; s < 2; ++s) {
      const float* p = lan + (cg * 64 + ct * 16 + cl) * DD + s * 32 + o * 8;
      bu[ct][s][0] = *(const float4*)p;
      bu[ct][s][1] = *(const float4*)(p + 4);
    }

  // ---- prologue: stage chunks 0,1 (8 DMAs in flight) ----
  stage(0, smem);
  stage(1, smem + CHB);

  // ---- convert B fragments to fp16 ----
  f16x8 bf[4][2];
#pragma unroll
  for (int ct = 0; ct < 4; ++ct)
#pragma unroll
    for (int s = 0; s < 2; ++s) {
      union { f16x8 v; fp16x2 h[4]; } U;
      U.h[0] = __builtin_amdgcn_cvt_pkrtz(bu[ct][s][0].x, bu[ct][s][0].y);
      U.h[1] = __builtin_amdgcn_cvt_pkrtz(bu[ct][s][0].z, bu[ct][s][0].w);
      U.h[2] = __builtin_amdgcn_cvt_pkrtz(bu[ct][s][1].x, bu[ct][s][1].y);
      U.h[3] = __builtin_amdgcn_cvt_pkrtz(bu[ct][s][1].z, bu[ct][s][1].w);
      bf[ct][s] = U.v;
    }

  float m0[4], m1[4];
#pragma unroll
  for (int ct = 0; ct < 4; ++ct) { m0[ct] = -INFINITY; m1[ct] = -INFINITY; }

  auto compute = [&](const char* buf) {
#pragma unroll
    for (int rt = 0; rt < 4; ++rt) {
      const int row = rt * 16 + cl;              // all 64 rows of the chunk
      const int rx = row & 7;
      const char* rp = buf + row * 256;
      float4 u00 = *(const float4*)(rp + ((((o * 2 + 0) ^ rx)) << 4));
      float4 u01 = *(const float4*)(rp + ((((o * 2 + 1) ^ rx)) << 4));
      float4 u10 = *(const float4*)(rp + ((8 + ((o * 2 + 0) ^ rx)) << 4));
      float4 u11 = *(const float4*)(rp + ((8 + ((o * 2 + 1) ^ rx)) << 4));
      union { f16x8 v; fp16x2 h[4]; } A0, A1;
      A0.h[0] = __builtin_amdgcn_cvt_pkrtz(u00.x, u00.y);
      A0.h[1] = __builtin_amdgcn_cvt_pkrtz(u00.z, u00.w);
      A0.h[2] = __builtin_amdgcn_cvt_pkrtz(u01.x, u01.y);
      A0.h[3] = __builtin_amdgcn_cvt_pkrtz(u01.z, u01.w);
      A1.h[0] = __builtin_amdgcn_cvt_pkrtz(u10.x, u10.y);
      A1.h[1] = __builtin_amdgcn_cvt_pkrtz(u10.z, u10.w);
      A1.h[2] = __builtin_amdgcn_cvt_pkrtz(u11.x, u11.y);
      A1.h[3] = __builtin_amdgcn_cvt_pkrtz(u11.z, u11.w);
#pragma unroll
      for (int ct = 0; ct < 4; ++ct) {
        f32x4 acc = {0.f, 0.f, 0.f, 0.f};
        acc = __builtin_amdgcn_mfma_f32_16x16x32_f16(A0.v, bf[ct][0], acc, 0, 0, 0);
        acc = __builtin_amdgcn_mfma_f32_16x16x32_f16(A1.v, bf[ct][1], acc, 0, 0, 0);
        float h1 = fmaxf(acc[0], acc[1]), q1 = fminf(acc[0], acc[1]);
        float h2 = fmaxf(acc[2], acc[3]), q2 = fminf(acc[2], acc[3]);
        float M0 = fmaxf(h1, h2);
        float M1 = fmaxf(fminf(h1, h2), fmaxf(q1, q2));
        float old0 = m0[ct];
        m0[ct] = fmaxf(old0, M0);
        m1[ct] = fmaxf(m1[ct], fmaxf(fminf(old0, M0), M1));
      }
    }
  };

  // ---- main loop: depth-2 counted-vmcnt pipeline, 1 raw barrier/chunk ----
#pragma unroll 1
  for (int ch = 0; ch < NCHUNK; ++ch) {
    if (ch + 2 < NCHUNK) {
      stage(ch + 2, smem + (size_t)((ch + 2) & 3) * CHB);
      asm volatile("s_waitcnt vmcnt(8)" ::: "memory");   // my ch loads done
    } else if (ch + 1 < NCHUNK) {
      asm volatile("s_waitcnt vmcnt(4)" ::: "memory");
    } else {
      asm volatile("s_waitcnt vmcnt(0)" ::: "memory");
    }
    __builtin_amdgcn_s_barrier();            // everyone's ch loads done
    __builtin_amdgcn_sched_barrier(0);
    compute(smem + (size_t)(ch & 3) * CHB);
  }

  // ---- merge across the 4 k-octet row-groups; store per-wave partials ----
#pragma unroll
  for (int ct = 0; ct < 4; ++ct) {
#pragma unroll
    for (int off = 16; off <= 32; off <<= 1) {
      float p0 = __shfl_xor(m0[ct], off);
      float p1 = __shfl_xor(m1[ct], off);
      float n1 = fmaxf(fminf(m0[ct], p0), fmaxf(m1[ct], p1));
      m0[ct] = fmaxf(m0[ct], p0);
      m1[ct] = n1;
    }
    if (lane < 16) {
      const int col = cg * 64 + ct * 16 + lane;
      max0P[((size_t)a * 2 + half) * BB + col] = m0[ct];
      max1P[((size_t)a * 2 + half) * BB + col] = m1[ct];
    }
  }
}

// ---------------------------------------------------------------------------
// Kernel 2: per row b, merge the two v-half partials per a, LSE over 511
// logits, loss_b = LSE - diag.
// ---------------------------------------------------------------------------
__global__ __launch_bounds__(256) void lse_kernel(
    const float* __restrict__ max0P, const float* __restrict__ max1P,
    float* __restrict__ lossb)
{
  __shared__ float red[256];
  __shared__ float diag;
  const int b = blockIdx.x;
  const int t = threadIdx.x;     // t = a
  float p00 = max0P[((size_t)t * 2 + 0) * BB + b];
  float p01 = max0P[((size_t)t * 2 + 1) * BB + b];
  float p10 = max1P[((size_t)t * 2 + 0) * BB + b];
  float p11 = max1P[((size_t)t * 2 + 1) * BB + b];
  float x0 = fmaxf(p00, p01);                                  // global max
  float x1m = fmaxf(fminf(p00, p01), fmaxf(p10, p11));         // global 2nd
  float x1 = (t == b) ? -INFINITY : x1m;
  if (t == b) diag = x0;
  red[t] = fmaxf(x0, x1);
  __syncthreads();
  for (int s = 128; s > 0; s >>= 1) {
    if (t < s) red[t] = fmaxf(red[t], red[t + s]);
    __syncthreads();
  }
  float M = red[0];
  __syncthreads();
  float e = expf(x0 - M) + ((t == b) ? 0.0f : expf(x1 - M));
  red[t] = e;
  __syncthreads();
  for (int s = 128; s > 0; s >>= 1) {
    if (t < s) red[t] = red[t] + red[t + s];
    __syncthreads();
  }
  if (t == 0) lossb[b] = logf(red[0]) + M - diag;
}

__global__ __launch_bounds__(256) void mean_kernel(
    const float* __restrict__ lossb, float* __restrict__ out)
{
  __shared__ float red[256];
  const int t = threadIdx.x;
  red[t] = lossb[t];
  __syncthreads();
  for (int s = 128; s > 0; s >>= 1) {
    if (t < s) red[t] += red[t + s];
    __syncthreads();
  }
  if (t == 0) out[0] = red[0] * (1.0f / 256.0f);
}

extern "C" void kernel_launch(void* const* d_in, const int* in_sizes, int n_in,
                              void* d_out, int out_size, void* d_ws, size_t ws_size,
                              hipStream_t stream) {
  const float* F   = (const float*)d_in[0];   // fusion_fs [256,4096,64] fp32
  const float* lan = (const float*)d_in[1];   // lan_fs    [256,1,64]   fp32
  float* ws = (float*)d_ws;
  float* max0P = ws;                // [256*2*256]
  float* max1P = ws + 131072;       // [256*2*256]
  float* lossb = ws + 262144;       // [256]

  const int shmem = 4 * CHB;        // 64 KB dynamic per block
  hipFuncSetAttribute((const void*)topk_sim_kernel,
                      hipFuncAttributeMaxDynamicSharedMemorySize, shmem);
  topk_sim_kernel<<<512, 256, shmem, stream>>>(F, lan, max0P, max1P);
  lse_kernel<<<256, 256, 0, stream>>>(max0P, max1P, lossb);
  mean_kernel<<<1, 256, 0, stream>>>(lossb, (float*)d_out);
}

// Round 13
// 70.569 us; speedup vs baseline: 1.1060x; 1.1060x over previous
//
#include <hip/hip_runtime.h>
#include <math.h>

#define BB 256
#define VV 4096
#define DD 64
#define NCHUNK 32
#define CHB 32768   // chunk bytes: 128 rows x 64 d x 4 B
#define NBUF 5      // 5 x 32 KB = 160 KB LDS, depth-3 pipeline

typedef __attribute__((ext_vector_type(8))) _Float16 f16x8;
typedef __attribute__((ext_vector_type(2))) __fp16 fp16x2;   // cvt_pkrtz return type
typedef __attribute__((ext_vector_type(4))) float f32x4;
typedef __attribute__((address_space(3))) void lds_void_t;
typedef const __attribute__((address_space(1))) void gvoid_t;

// ---------------------------------------------------------------------------
// Kernel 1: one block (512 thr, 8 waves) per a.  wave = rg*4+cg.
// r10 structure (best: 72us) with FIVE 32KB LDS buffers -> depth-3 counted
// vmcnt(12), same 32-barrier count.  r11/r12 showed: more barriers = worse,
// domain-split = worse; the residual stall is last-DMA delivery jitter =>
// add in-flight headroom (64->96 KB) at constant barrier count.
// Overwrite safety: stage(ch+3) -> buf (ch+3)%5, last read by compute(ch-2);
// every wave's compute(ch-2) precedes its barrier(ch-1), which precedes any
// wave's stage at iter ch.  Merge scratch aliases buf0 after the loop.
// ---------------------------------------------------------------------------
__global__ __launch_bounds__(512) void topk_sim_kernel(
    const float* __restrict__ F, const float* __restrict__ lan,
    float* __restrict__ max0T, float* __restrict__ max1T)
{
  extern __shared__ __align__(16) char smem[];   // 5 x 32KB chunk buffers
  float* mrg = (float*)smem;                     // [8][64][2] alias, post-loop

  const int t = threadIdx.x;
  const int a = blockIdx.x;
  const int wave = t >> 6;
  const int lane = t & 63;
  const int cl = lane & 15;      // row (A) / col (B/C) within 16x16 tile
  const int o  = lane >> 4;      // k-octet group
  const int rg = wave >> 2;      // row half
  const int cg = wave & 3;       // col quarter

  const char* gFa = (const char*)(F + (size_t)a * VV * DD);

  // pre-swizzled per-lane global source offsets (G21: linear LDS dest,
  // inverse-swizzled source, swizzled read).
  int soff[4];
#pragma unroll
  for (int i = 0; i < 4; ++i) {
    int row = wave * 16 + i * 4 + o;             // row in [0,128)
    soff[i] = row * 256 + (cl ^ (row & 7)) * 16;
  }

  auto stage = [&](int ch, char* buf) {
    const char* g = gFa + (size_t)ch * CHB;
    char* dst = buf + wave * 4096;               // wave-uniform base
#pragma unroll
    for (int i = 0; i < 4; ++i) {
      __builtin_amdgcn_global_load_lds(
          (gvoid_t*)(g + soff[i]),
          (lds_void_t*)(dst + i * 1024), 16, 0, 0);
    }
  };

  // ---- B fragment GLOBAL LOADS FIRST (older than all staging DMAs) ----
  float4 bu[4][2][2];
#pragma unroll
  for (int ct = 0; ct < 4; ++ct)
#pragma unroll
    for (int s = 0; s < 2; ++s) {
      const float* p = lan + (cg * 64 + ct * 16 + cl) * DD + s * 32 + o * 8;
      bu[ct][s][0] = *(const float4*)p;
      bu[ct][s][1] = *(const float4*)(p + 4);
    }

  // ---- prologue: stage chunks 0,1,2 (12 DMAs in flight) ----
  stage(0, smem);
  stage(1, smem + CHB);
  stage(2, smem + 2 * CHB);

  // ---- convert B fragments to fp16 ----
  f16x8 bf[4][2];
#pragma unroll
  for (int ct = 0; ct < 4; ++ct)
#pragma unroll
    for (int s = 0; s < 2; ++s) {
      union { f16x8 v; fp16x2 h[4]; } U;
      U.h[0] = __builtin_amdgcn_cvt_pkrtz(bu[ct][s][0].x, bu[ct][s][0].y);
      U.h[1] = __builtin_amdgcn_cvt_pkrtz(bu[ct][s][0].z, bu[ct][s][0].w);
      U.h[2] = __builtin_amdgcn_cvt_pkrtz(bu[ct][s][1].x, bu[ct][s][1].y);
      U.h[3] = __builtin_amdgcn_cvt_pkrtz(bu[ct][s][1].z, bu[ct][s][1].w);
      bf[ct][s] = U.v;
    }

  float m0[4], m1[4];
#pragma unroll
  for (int ct = 0; ct < 4; ++ct) { m0[ct] = -INFINITY; m1[ct] = -INFINITY; }

  auto compute = [&](const char* buf) {
#pragma unroll
    for (int rt = 0; rt < 4; ++rt) {
      const int row = rg * 64 + rt * 16 + cl;
      const int rx = row & 7;
      const char* rp = buf + row * 256;
      float4 u00 = *(const float4*)(rp + ((((o * 2 + 0) ^ rx)) << 4));
      float4 u01 = *(const float4*)(rp + ((((o * 2 + 1) ^ rx)) << 4));
      float4 u10 = *(const float4*)(rp + ((8 + ((o * 2 + 0) ^ rx)) << 4));
      float4 u11 = *(const float4*)(rp + ((8 + ((o * 2 + 1) ^ rx)) << 4));
      union { f16x8 v; fp16x2 h[4]; } A0, A1;
      A0.h[0] = __builtin_amdgcn_cvt_pkrtz(u00.x, u00.y);
      A0.h[1] = __builtin_amdgcn_cvt_pkrtz(u00.z, u00.w);
      A0.h[2] = __builtin_amdgcn_cvt_pkrtz(u01.x, u01.y);
      A0.h[3] = __builtin_amdgcn_cvt_pkrtz(u01.z, u01.w);
      A1.h[0] = __builtin_amdgcn_cvt_pkrtz(u10.x, u10.y);
      A1.h[1] = __builtin_amdgcn_cvt_pkrtz(u10.z, u10.w);
      A1.h[2] = __builtin_amdgcn_cvt_pkrtz(u11.x, u11.y);
      A1.h[3] = __builtin_amdgcn_cvt_pkrtz(u11.z, u11.w);
#pragma unroll
      for (int ct = 0; ct < 4; ++ct) {
        f32x4 acc = {0.f, 0.f, 0.f, 0.f};
        acc = __builtin_amdgcn_mfma_f32_16x16x32_f16(A0.v, bf[ct][0], acc, 0, 0, 0);
        acc = __builtin_amdgcn_mfma_f32_16x16x32_f16(A1.v, bf[ct][1], acc, 0, 0, 0);
        float h1 = fmaxf(acc[0], acc[1]), q1 = fminf(acc[0], acc[1]);
        float h2 = fmaxf(acc[2], acc[3]), q2 = fminf(acc[2], acc[3]);
        float M0 = fmaxf(h1, h2);
        float M1 = fmaxf(fminf(h1, h2), fmaxf(q1, q2));
        float old0 = m0[ct];
        m0[ct] = fmaxf(old0, M0);
        m1[ct] = fmaxf(m1[ct], fmaxf(fminf(old0, M0), M1));
      }
    }
  };

  // ---- main loop: depth-3 counted-vmcnt pipeline, 1 raw barrier/chunk ----
  int bcur = 0;     // buf index of chunk ch
  int bnxt = 3;     // buf index of chunk ch+3
#pragma unroll 1
  for (int ch = 0; ch < NCHUNK; ++ch) {
    if (ch + 3 < NCHUNK) {
      stage(ch + 3, smem + (size_t)bnxt * CHB);
      asm volatile("s_waitcnt vmcnt(12)" ::: "memory");   // ch delivered
    } else {
      const int rem = NCHUNK - 1 - ch;   // chunks outstanding beyond ch
      if (rem == 2)      asm volatile("s_waitcnt vmcnt(8)" ::: "memory");
      else if (rem == 1) asm volatile("s_waitcnt vmcnt(4)" ::: "memory");
      else               asm volatile("s_waitcnt vmcnt(0)" ::: "memory");
    }
    __builtin_amdgcn_s_barrier();            // everyone's ch loads done
    __builtin_amdgcn_sched_barrier(0);
    compute(smem + (size_t)bcur * CHB);
    bcur = (bcur == NBUF - 1) ? 0 : bcur + 1;
    bnxt = (bnxt == NBUF - 1) ? 0 : bnxt + 1;
  }

  __syncthreads();   // all LDS reads done; safe to alias buf0 as mrg

  // ---- merge across the 4 k-octet row-groups within the wave ----
#pragma unroll
  for (int ct = 0; ct < 4; ++ct) {
#pragma unroll
    for (int off = 16; off <= 32; off <<= 1) {
      float p0 = __shfl_xor(m0[ct], off);
      float p1 = __shfl_xor(m1[ct], off);
      float n1 = fmaxf(fminf(m0[ct], p0), fmaxf(m1[ct], p1));
      m0[ct] = fmaxf(m0[ct], p0);
      m1[ct] = n1;
    }
    if (lane < 16) {
      mrg[(wave * 64 + ct * 16 + lane) * 2 + 0] = m0[ct];
      mrg[(wave * 64 + ct * 16 + lane) * 2 + 1] = m1[ct];
    }
  }
  __syncthreads();

  // ---- merge the 2 row-half waves of each col group; store ----
  if (t < BB) {
    const int cg2 = t >> 6, lc = t & 63;   // global col == t
    float a0 = mrg[(cg2 * 64 + lc) * 2 + 0];
    float a1 = mrg[(cg2 * 64 + lc) * 2 + 1];
    float b0 = mrg[((4 + cg2) * 64 + lc) * 2 + 0];
    float b1 = mrg[((4 + cg2) * 64 + lc) * 2 + 1];
    float M0 = fmaxf(a0, b0);
    float M1 = fmaxf(fminf(a0, b0), fmaxf(a1, b1));
    max0T[a * BB + t] = M0;
    max1T[a * BB + t] = M1;
  }
}

// ---------------------------------------------------------------------------
// Kernel 2: per row b, LSE over 511 logits, loss_b = LSE - diag.
// ---------------------------------------------------------------------------
__global__ __launch_bounds__(256) void lse_kernel(
    const float* __restrict__ max0T, const float* __restrict__ max1T,
    float* __restrict__ lossb)
{
  __shared__ float red[256];
  __shared__ float diag;
  const int b = blockIdx.x;
  const int t = threadIdx.x;     // t = a
  float x0 = max0T[t * BB + b];
  float x1 = (t == b) ? -INFINITY : max1T[t * BB + b];
  if (t == b) diag = x0;
  red[t] = fmaxf(x0, x1);
  __syncthreads();
  for (int s = 128; s > 0; s >>= 1) {
    if (t < s) red[t] = fmaxf(red[t], red[t + s]);
    __syncthreads();
  }
  float M = red[0];
  __syncthreads();
  float e = expf(x0 - M) + ((t == b) ? 0.0f : expf(x1 - M));
  red[t] = e;
  __syncthreads();
  for (int s = 128; s > 0; s >>= 1) {
    if (t < s) red[t] = red[t] + red[t + s];
    __syncthreads();
  }
  if (t == 0) lossb[b] = logf(red[0]) + M - diag;
}

__global__ __launch_bounds__(256) void mean_kernel(
    const float* __restrict__ lossb, float* __restrict__ out)
{
  __shared__ float red[256];
  const int t = threadIdx.x;
  red[t] = lossb[t];
  __syncthreads();
  for (int s = 128; s > 0; s >>= 1) {
    if (t < s) red[t] += red[t + s];
    __syncthreads();
  }
  if (t == 0) out[0] = red[0] * (1.0f / 256.0f);
}

extern "C" void kernel_launch(void* const* d_in, const int* in_sizes, int n_in,
                              void* d_out, int out_size, void* d_ws, size_t ws_size,
                              hipStream_t stream) {
  const float* F   = (const float*)d_in[0];   // fusion_fs [256,4096,64] fp32
  const float* lan = (const float*)d_in[1];   // lan_fs    [256,1,64]   fp32
  float* ws = (float*)d_ws;
  float* max0T = ws;                // [256*256]
  float* max1T = ws + 65536;        // [256*256]
  float* lossb = ws + 131072;       // [256]

  const int shmem = NBUF * CHB;     // 163840 B = full 160 KB LDS
  hipFuncSetAttribute((const void*)topk_sim_kernel,
                      hipFuncAttributeMaxDynamicSharedMemorySize, shmem);
  topk_sim_kernel<<<256, 512, shmem, stream>>>(F, lan, max0T, max1T);
  lse_kernel<<<256, 256, 0, stream>>>(max0T, max1T, lossb);
  mean_kernel<<<1, 256, 0, stream>>>(lossb, (float*)d_out);
}